// Round 1
// baseline (503.837 us; speedup 1.0000x reference)
//
#include <hip/hip_runtime.h>

// ---------------------------------------------------------------------------
// Self_Attention_30193620091602  (N=256, A=1024, K_DIM=1), fp32 in/out.
// bf16-MFMA pipeline with split-bf16 (hi/lo, 3-pass) on the q/logits path
// for near-fp32 accuracy; plain bf16 for v / PV / out-proj.
// Scratch: d_out[0..134MB) holds qT/v/attT (dead before K5 overwrites d_out);
// d_ws holds om + split weights + klT  (requires ws_size >= ~37 MB).
// ---------------------------------------------------------------------------

typedef unsigned short u16;
typedef unsigned int   uint;
using f32x4  = __attribute__((ext_vector_type(4))) float;
using bf16x8 = __attribute__((ext_vector_type(8))) short;
using u16x4  = __attribute__((ext_vector_type(4))) u16;

#define DEVI static __device__ __forceinline__

DEVI u16 f2bf(float f){
  union { float f; uint u; } v; v.f = f;
  uint r = v.u + 0x7fffu + ((v.u >> 16) & 1u);   // round-to-nearest-even
  return (u16)(r >> 16);
}
DEVI float bf2f(u16 h){
  union { uint u; float f; } v; v.u = ((uint)h) << 16;
  return v.f;
}

typedef const uint __attribute__((address_space(1)))* as1_cuintp;
typedef uint __attribute__((address_space(3)))* as3_uintp;

DEVI void gl_lds16(const void* g, void* l){
  __builtin_amdgcn_global_load_lds((as1_cuintp)g, (as3_uintp)l, 16, 0, 0);
}

// Stage ROWS x 64 bf16 tile (rowStride elems in global) into LDS.
// LDS layout: elem(row,k) at row*64 + ((k/8 ^ (row&7))*8 + k%8)  (16B-chunk
// XOR swizzle; global_load_lds writes linearly, so the SOURCE is pre-swizzled).
template<int ROWS>
DEVI void stage_tile(const u16* __restrict__ g, long long rowStride,
                     u16* lds, int lane, int wave){
  constexpr int NLD = ROWS >> 3;            // 1KB wave-loads
  #pragma unroll
  for (int j = 0; j < NLD/4; ++j){
    int r0  = (wave + 4*j) << 3;
    int row = r0 + (lane >> 3);
    const u16* src = g + (long long)row * rowStride
                       + (((lane & 7) ^ (lane >> 3)) << 3);
    gl_lds16(src, lds + r0 * 64);
  }
}

// MFMA A/B fragment read from the swizzled [*,64] LDS tile.
DEVI bf16x8 ldfrag(const u16* s, int rbase, int kk, int lane){
  int row = rbase + (lane & 15);
  int c   = (kk << 2) + (lane >> 4);
  return *(const bf16x8*)(s + row*64 + ((c ^ (row & 7)) << 3));
}

// ---------------------------------------------------------------------------
// Generic GEMM: C[M x N] = A[M x K] * B^T (B stored N x K) (+bias)
// AF32 : A is fp32 in global; reg-stage + convert to bf16 hi(/lo) into LDS.
// SPLIT: 3-pass split-bf16 (needs Bl; for AF32 the lo tile is built on the fly)
// WMODE: 0 = fp32 natural (+bias)      (out-proj)
//        1 = bf16 natural (+bias)      (v, om)
//        2 = bf16 hi/lo pair, stored per-b transposed: C[b][c][m]  (qT)
// bStrideB: if nonzero, B is batched per b = row/256 (attT).
// ---------------------------------------------------------------------------
template<int AF32, int SPLIT, int WMODE>
__global__ __launch_bounds__(256, 2)
void k_gemm(const void* __restrict__ Ag,
            const u16* __restrict__ Bhg, const u16* __restrict__ Blg,
            int N, int K, int tnCount, long long bStrideB,
            const float* __restrict__ bias,
            void* __restrict__ Co, u16* __restrict__ Cl)
{
  __shared__ __align__(16) u16 sA [128*64];
  __shared__ __align__(16) u16 sB [128*64];
  __shared__ __align__(16) u16 sAl[SPLIT ? 128*64 : 8];
  __shared__ __align__(16) u16 sBl[SPLIT ? 128*64 : 8];

  const int tid  = threadIdx.x;
  const int lane = tid & 63;
  const int wave = tid >> 6;
  const int wm   = wave >> 1;
  const int wn   = wave & 1;
  const int tn   = blockIdx.x % tnCount;
  const int tm   = blockIdx.x / tnCount;
  const int tileM = tm << 7;
  const int tileN = tn << 7;

  const long long bOff = bStrideB ? (long long)(tileM >> 8) * bStrideB : 0;
  const u16* Bh_t = Bhg + bOff + (long long)tileN * K;
  const u16* Bl_t = SPLIT ? (Blg + bOff + (long long)tileN * K) : (const u16*)0;

  f32x4 acc[4][4];
  #pragma unroll
  for (int i=0;i<4;i++)
    #pragma unroll
    for (int j=0;j<4;j++){
      acc[i][j][0]=0.f; acc[i][j][1]=0.f; acc[i][j][2]=0.f; acc[i][j][3]=0.f;
    }

  for (int kt = 0; kt < K; kt += 64){
    if (AF32){
      // flat float4 id f = tid + 256j -> row=f>>4, 16B col chunk=f&15 (coalesced)
      #pragma unroll
      for (int j=0;j<8;j++){
        int f   = tid + (j << 8);
        int row = f >> 4;
        int c16 = f & 15;
        f32x4 t = *(const f32x4*)((const float*)Ag
                   + (long long)(tileM + row)*K + kt + (c16 << 2));
        u16x4 h4, l4;
        #pragma unroll
        for (int e=0;e<4;e++){
          u16 h = f2bf(t[e]);
          h4[e] = h;
          if (SPLIT) l4[e] = f2bf(t[e] - bf2f(h));
        }
        int cb  = c16 >> 1;
        int off = row*64 + ((cb ^ (row & 7)) << 3) + ((c16 & 1) << 2);
        *(u16x4*)(sA + off) = h4;
        if (SPLIT) *(u16x4*)(sAl + off) = l4;
      }
    } else {
      stage_tile<128>((const u16*)Ag + (long long)tileM * K + kt, K, sA, lane, wave);
    }
    stage_tile<128>(Bh_t + kt, K, sB, lane, wave);
    if (SPLIT) stage_tile<128>(Bl_t + kt, K, sBl, lane, wave);
    __syncthreads();

    #pragma unroll
    for (int kk=0;kk<2;kk++){
      bf16x8 a[4], b[4], al[4], bl[4];
      #pragma unroll
      for (int i=0;i<4;i++){
        a[i] = ldfrag(sA, wm*64 + i*16, kk, lane);
        b[i] = ldfrag(sB, wn*64 + i*16, kk, lane);
        if (SPLIT){
          al[i] = ldfrag(sAl, wm*64 + i*16, kk, lane);
          bl[i] = ldfrag(sBl, wn*64 + i*16, kk, lane);
        }
      }
      #pragma unroll
      for (int mt=0;mt<4;mt++)
        #pragma unroll
        for (int nt=0;nt<4;nt++){
          acc[mt][nt] = __builtin_amdgcn_mfma_f32_16x16x32_bf16(a[mt], b[nt], acc[mt][nt], 0,0,0);
          if (SPLIT){
            acc[mt][nt] = __builtin_amdgcn_mfma_f32_16x16x32_bf16(al[mt], b[nt],  acc[mt][nt], 0,0,0);
            acc[mt][nt] = __builtin_amdgcn_mfma_f32_16x16x32_bf16(a[mt],  bl[nt], acc[mt][nt], 0,0,0);
          }
        }
    }
    __syncthreads();
  }

  // Epilogue. C/D frag: col = lane&15, row = (lane>>4)*4 + reg  [m89-verified]
  #pragma unroll
  for (int mt=0;mt<4;mt++)
    #pragma unroll
    for (int nt=0;nt<4;nt++){
      const int rl = wm*64 + mt*16 + ((lane >> 4) << 2);
      const int cl = wn*64 + nt*16 + (lane & 15);
      const int gr = tileM + rl;
      const int gc = tileN + cl;
      const float bb = bias ? bias[gc] : 0.f;
      f32x4 v = acc[mt][nt];
      if (WMODE == 0){
        float* o = (float*)Co + (long long)gr * N + gc;
        #pragma unroll
        for (int r=0;r<4;r++) o[(long long)r * N] = v[r] + bb;
      } else if (WMODE == 1){
        u16* o = (u16*)Co + (long long)gr * N + gc;
        #pragma unroll
        for (int r=0;r<4;r++) o[(long long)r * N] = f2bf(v[r] + bb);
      } else {
        const int bidx = gr >> 8, m = gr & 255;       // 4 consecutive m -> 8B store
        const long long off = ((long long)bidx << 16) + ((long long)gc << 8) + m;
        u16x4 h4, l4;
        #pragma unroll
        for (int r=0;r<4;r++){
          float f = v[r] + bb;
          u16 h = f2bf(f);
          h4[r] = h;
          l4[r] = f2bf(f - bf2f(h));
        }
        *(u16x4*)((u16*)Co + off) = h4;
        *(u16x4*)(Cl + off)       = l4;
      }
    }
}

// ---------------------------------------------------------------------------
// K3: logits[b,n,:] = sum_m klT[n][m] * qT[b][:,m]  (split 3-pass), then
// row-softmax over qq (full 256 in-block), store attT[b][qq][n] bf16.
// Block = (b, ntile): 64 rows x 256 cols, K=256.
// ---------------------------------------------------------------------------
__global__ __launch_bounds__(256, 1)
void k_logits(const u16* __restrict__ qTh, const u16* __restrict__ qTl,
              const u16* __restrict__ klTh, const u16* __restrict__ klTl,
              u16* __restrict__ attT)
{
  __shared__ __align__(16) union U {
    struct S { u16 Ah[64*64]; u16 Al[64*64]; u16 Bh[256*64]; u16 Bl[256*64]; } s; // 80 KB
    float L[64*260];                                                              // 65 KB
  } u;
  __shared__ float rmax[64], rinv[64];

  const int tid  = threadIdx.x;
  const int lane = tid & 63;
  const int wave = tid >> 6;
  const int bidx  = blockIdx.x >> 2;
  const int ntile = blockIdx.x & 3;

  f32x4 acc[4][4];
  #pragma unroll
  for (int i=0;i<4;i++)
    #pragma unroll
    for (int j=0;j<4;j++){
      acc[i][j][0]=0.f; acc[i][j][1]=0.f; acc[i][j][2]=0.f; acc[i][j][3]=0.f;
    }

  for (int kt=0; kt<256; kt+=64){
    stage_tile<64> (klTh + (ntile << 6)*256 + kt, 256, u.s.Ah, lane, wave);
    stage_tile<64> (klTl + (ntile << 6)*256 + kt, 256, u.s.Al, lane, wave);
    stage_tile<256>(qTh + ((long long)bidx << 16) + kt, 256, u.s.Bh, lane, wave);
    stage_tile<256>(qTl + ((long long)bidx << 16) + kt, 256, u.s.Bl, lane, wave);
    __syncthreads();
    #pragma unroll
    for (int kk=0;kk<2;kk++){
      bf16x8 a[4], al[4], b[4], bl[4];
      #pragma unroll
      for (int i=0;i<4;i++){
        a[i]  = ldfrag(u.s.Ah, i*16, kk, lane);
        al[i] = ldfrag(u.s.Al, i*16, kk, lane);
        b[i]  = ldfrag(u.s.Bh, wave*64 + i*16, kk, lane);
        bl[i] = ldfrag(u.s.Bl, wave*64 + i*16, kk, lane);
      }
      #pragma unroll
      for (int mt=0;mt<4;mt++)
        #pragma unroll
        for (int nt=0;nt<4;nt++){
          acc[mt][nt] = __builtin_amdgcn_mfma_f32_16x16x32_bf16(a[mt],  b[nt],  acc[mt][nt], 0,0,0);
          acc[mt][nt] = __builtin_amdgcn_mfma_f32_16x16x32_bf16(al[mt], b[nt],  acc[mt][nt], 0,0,0);
          acc[mt][nt] = __builtin_amdgcn_mfma_f32_16x16x32_bf16(a[mt],  bl[nt], acc[mt][nt], 0,0,0);
        }
    }
    __syncthreads();
  }

  // dump logits (K_DIM=1 => scale 1) into L [64][260]
  #pragma unroll
  for (int mt=0;mt<4;mt++)
    #pragma unroll
    for (int nt=0;nt<4;nt++){
      const int r0 = mt*16 + ((lane >> 4) << 2);
      const int c  = wave*64 + nt*16 + (lane & 15);
      #pragma unroll
      for (int r=0;r<4;r++) u.L[(r0 + r)*260 + c] = acc[mt][nt][r];
    }
  __syncthreads();

  // row max & sum(exp): 4 threads per row
  {
    const int row = tid >> 2, sub = tid & 3;
    const float* Lr = &u.L[row*260 + sub*64];
    float mx = -3.4e38f;
    for (int i=0;i<64;i++) mx = fmaxf(mx, Lr[i]);
    mx = fmaxf(mx, __shfl_xor(mx, 1, 64));
    mx = fmaxf(mx, __shfl_xor(mx, 2, 64));
    float s = 0.f;
    for (int i=0;i<64;i++) s += __expf(Lr[i] - mx);
    s += __shfl_xor(s, 1, 64);
    s += __shfl_xor(s, 2, 64);
    if (sub == 0){ rmax[row] = mx; rinv[row] = 1.f / s; }
  }
  __syncthreads();

  // transposed store: thread qq writes attT[b][qq][ntile*64 .. +64)
  {
    const int qq = tid;
    u16* dst = attT + ((long long)bidx << 16) + qq*256 + (ntile << 6);
    #pragma unroll
    for (int n0=0;n0<64;n0+=8){
      bf16x8 pk;
      #pragma unroll
      for (int e=0;e<8;e++){
        int n = n0 + e;
        float v = __expf(u.L[n*260 + qq] - rmax[n]) * rinv[n];
        pk[e] = (short)f2bf(v);
      }
      *(bf16x8*)(dst + n0) = pk;
    }
  }
}

// split a fp32 array into bf16 hi/lo
__global__ void k_split(const float* __restrict__ w, u16* __restrict__ hi,
                        u16* __restrict__ lo, int n4){
  int i = blockIdx.x * blockDim.x + threadIdx.x;
  if (i >= n4) return;
  f32x4 v = ((const f32x4*)w)[i];
  u16x4 h, l;
  #pragma unroll
  for (int e=0;e<4;e++){
    u16 hh = f2bf(v[e]);
    h[e] = hh;
    l[e] = f2bf(v[e] - bf2f(hh));
  }
  ((u16x4*)hi)[i] = h;
  ((u16x4*)lo)[i] = l;
}

// klin[r] = x[r,:].Wk + bk, stored transposed klT[n][b] as bf16 hi/lo
__global__ __launch_bounds__(64)
void k_klin(const float* __restrict__ x, const float* __restrict__ Wk,
            const float* __restrict__ bk,
            u16* __restrict__ klTh, u16* __restrict__ klTl){
  const int r = blockIdx.x;
  const int t = threadIdx.x;
  const f32x4* xr = (const f32x4*)(x + (long long)r * 1024);
  const f32x4* wr = (const f32x4*)Wk;
  float s = 0.f;
  #pragma unroll
  for (int j=0;j<4;j++){
    int f4 = t + (j << 6);
    f32x4 a = xr[f4];
    f32x4 w = wr[f4];
    s += a[0]*w[0] + a[1]*w[1] + a[2]*w[2] + a[3]*w[3];
  }
  #pragma unroll
  for (int m=32;m>0;m>>=1) s += __shfl_xor(s, m, 64);
  if (t == 0){
    const int bb = r >> 8, nn = r & 255;
    float kv = s + bk[0];
    u16 h = f2bf(kv);
    klTh[nn*256 + bb] = h;
    klTl[nn*256 + bb] = f2bf(kv - bf2f(h));
  }
}

extern "C" void kernel_launch(void* const* d_in, const int* in_sizes, int n_in,
                              void* d_out, int out_size, void* d_ws, size_t ws_size,
                              hipStream_t stream){
  (void)in_sizes; (void)n_in; (void)out_size; (void)ws_size;
  const float* x  = (const float*)d_in[0];
  const float* Wq = (const float*)d_in[1];
  const float* bq = (const float*)d_in[2];
  const float* Wk = (const float*)d_in[3];
  const float* bk = (const float*)d_in[4];
  const float* Wv = (const float*)d_in[5];
  const float* bv = (const float*)d_in[6];
  const float* Wo = (const float*)d_in[7];
  const float* bo = (const float*)d_in[8];

  // scratch carved from d_out (dead before K5 rewrites it) + d_ws
  char* ob = (char*)d_out;
  u16* qTh  = (u16*)(ob);                          // 33.5 MB
  u16* qTl  = (u16*)(ob + (size_t)33554432);       // 33.5 MB
  u16* vh   = (u16*)(ob + (size_t)67108864);       // 33.5 MB
  u16* attT = (u16*)(ob + (size_t)100663296);      // 33.5 MB
  char* wb = (char*)d_ws;
  u16* omh  = (u16*)(wb);                          // 33.5 MB
  u16* Wqh  = (u16*)(wb + (size_t)33554432);
  u16* Wql  = Wqh + 262144;
  u16* Wvh  = Wql + 262144;
  u16* Wvl  = Wvh + 262144;
  u16* Woh  = Wvl + 262144;
  u16* Wol  = Woh + 262144;
  u16* klTh = Wol + 262144;                        // 128 KB
  u16* klTl = klTh + 65536;                        // total ws ~36.9 MB

  k_split<<<256, 256, 0, stream>>>(Wq, Wqh, Wql, 65536);
  k_split<<<256, 256, 0, stream>>>(Wv, Wvh, Wvl, 65536);
  k_split<<<256, 256, 0, stream>>>(Wo, Woh, Wol, 65536);
  k_klin<<<65536, 64, 0, stream>>>(x, Wk, bk, klTh, klTl);

  // K1: qT (split, transposed bf16-pair out), N=256, K=1024
  k_gemm<1,1,2><<<1024, 256, 0, stream>>>(x, Wqh, Wql, 256, 1024, 2, 0, bq, qTh, qTl);
  // K2: v (plain), N=256, K=1024
  k_gemm<1,0,1><<<1024, 256, 0, stream>>>(x, Wvh, nullptr, 256, 1024, 2, 0, bv, vh, nullptr);
  // K3: logits + softmax -> attT
  k_logits<<<1024, 256, 0, stream>>>(qTh, qTl, klTh, klTl, attT);
  // K4: om = v @ att (B batched per b), N=256, K=256
  k_gemm<0,0,1><<<1024, 256, 0, stream>>>(vh, attT, nullptr, 256, 256, 2, 65536, nullptr, omh, nullptr);
  // K5: out = om @ Wo^T + bo (fp32 out), N=1024, K=256
  k_gemm<0,0,0><<<4096, 256, 0, stream>>>(omh, Woh, nullptr, 1024, 256, 8, 0, bo, d_out, nullptr);
}

// Round 3
// 423.991 us; speedup vs baseline: 1.1883x; 1.1883x over previous
//
#include <hip/hip_runtime.h>

// ---------------------------------------------------------------------------
// Self_Attention_30193620091602  (N=256, A=1024, K_DIM=1), fp32 in/out.
// R3: R1-proven pipeline, with v-projection + klin fused into k_vkl (reads x
// once for both; removes the separate k_klin pass). Q-projection (split-bf16,
// 3-pass) kept EXACTLY as R1's verified k_gemm<1,1,2>.
// Scratch: d_out[0..134MB) holds qT/v/attT (dead before K5 overwrites d_out);
// d_ws holds om + split weights + klT  (~37 MB).
// ---------------------------------------------------------------------------

typedef unsigned short u16;
typedef unsigned int   uint;
using f32x4  = __attribute__((ext_vector_type(4))) float;
using bf16x8 = __attribute__((ext_vector_type(8))) short;
using u16x4  = __attribute__((ext_vector_type(4))) u16;

#define DEVI static __device__ __forceinline__

DEVI u16 f2bf(float f){
  union { float f; uint u; } v; v.f = f;
  uint r = v.u + 0x7fffu + ((v.u >> 16) & 1u);   // round-to-nearest-even
  return (u16)(r >> 16);
}
DEVI float bf2f(u16 h){
  union { uint u; float f; } v; v.u = ((uint)h) << 16;
  return v.f;
}

typedef const uint __attribute__((address_space(1)))* as1_cuintp;
typedef uint __attribute__((address_space(3)))* as3_uintp;

DEVI void gl_lds16(const void* g, void* l){
  __builtin_amdgcn_global_load_lds((as1_cuintp)g, (as3_uintp)l, 16, 0, 0);
}

// Stage ROWS x 64 bf16 tile (rowStride elems in global) into LDS, NW waves.
// LDS layout: elem(row,k) at row*64 + ((k/8 ^ (row&7))*8 + k%8)  (16B-chunk
// XOR swizzle; global_load_lds writes linearly, so the SOURCE is pre-swizzled).
template<int ROWS, int NW>
DEVI void stage_tile(const u16* __restrict__ g, long long rowStride,
                     u16* lds, int lane, int wave){
  constexpr int NLD = ROWS >> 3;            // 1KB wave-loads
  #pragma unroll
  for (int j = 0; j < NLD/NW; ++j){
    int r0  = (wave + NW*j) << 3;
    int row = r0 + (lane >> 3);
    const u16* src = g + (long long)row * rowStride
                       + (((lane & 7) ^ (lane >> 3)) << 3);
    gl_lds16(src, lds + r0 * 64);
  }
}

// MFMA A/B fragment read from the swizzled [*,64] LDS tile.
DEVI bf16x8 ldfrag(const u16* s, int rbase, int kk, int lane){
  int row = rbase + (lane & 15);
  int c   = (kk << 2) + (lane >> 4);
  return *(const bf16x8*)(s + row*64 + ((c ^ (row & 7)) << 3));
}

// ---------------------------------------------------------------------------
// Generic GEMM: C[M x N] = A[M x K] * B^T (B stored N x K) (+bias)
// AF32 : A is fp32 in global; reg-stage + convert to bf16 hi(/lo) into LDS.
// SPLIT: 3-pass split-bf16 (needs Bl; for AF32 the lo tile is built on the fly)
// WMODE: 0 = fp32 natural (+bias)      (out-proj)
//        1 = bf16 natural (+bias)      (om)
//        2 = bf16 hi/lo pair, stored per-b transposed: C[b][c][m]  (qT)
// bStrideB: if nonzero, B is batched per b = row/256 (attT).
// ---------------------------------------------------------------------------
template<int AF32, int SPLIT, int WMODE>
__global__ __launch_bounds__(256, 2)
void k_gemm(const void* __restrict__ Ag,
            const u16* __restrict__ Bhg, const u16* __restrict__ Blg,
            int N, int K, int tnCount, long long bStrideB,
            const float* __restrict__ bias,
            void* __restrict__ Co, u16* __restrict__ Cl)
{
  __shared__ __align__(16) u16 sA [128*64];
  __shared__ __align__(16) u16 sB [128*64];
  __shared__ __align__(16) u16 sAl[SPLIT ? 128*64 : 8];
  __shared__ __align__(16) u16 sBl[SPLIT ? 128*64 : 8];

  const int tid  = threadIdx.x;
  const int lane = tid & 63;
  const int wave = tid >> 6;
  const int wm   = wave >> 1;
  const int wn   = wave & 1;
  const int tn   = blockIdx.x % tnCount;
  const int tm   = blockIdx.x / tnCount;
  const int tileM = tm << 7;
  const int tileN = tn << 7;

  const long long bOff = bStrideB ? (long long)(tileM >> 8) * bStrideB : 0;
  const u16* Bh_t = Bhg + bOff + (long long)tileN * K;
  const u16* Bl_t = SPLIT ? (Blg + bOff + (long long)tileN * K) : (const u16*)0;

  f32x4 acc[4][4];
  #pragma unroll
  for (int i=0;i<4;i++)
    #pragma unroll
    for (int j=0;j<4;j++){
      acc[i][j][0]=0.f; acc[i][j][1]=0.f; acc[i][j][2]=0.f; acc[i][j][3]=0.f;
    }

  for (int kt = 0; kt < K; kt += 64){
    if (AF32){
      // flat float4 id f = tid + 256j -> row=f>>4, 16B col chunk=f&15 (coalesced)
      #pragma unroll
      for (int j=0;j<8;j++){
        int f   = tid + (j << 8);
        int row = f >> 4;
        int c16 = f & 15;
        f32x4 t = *(const f32x4*)((const float*)Ag
                   + (long long)(tileM + row)*K + kt + (c16 << 2));
        u16x4 h4, l4;
        #pragma unroll
        for (int e=0;e<4;e++){
          u16 h = f2bf(t[e]);
          h4[e] = h;
          if (SPLIT) l4[e] = f2bf(t[e] - bf2f(h));
        }
        int cb  = c16 >> 1;
        int off = row*64 + ((cb ^ (row & 7)) << 3) + ((c16 & 1) << 2);
        *(u16x4*)(sA + off) = h4;
        if (SPLIT) *(u16x4*)(sAl + off) = l4;
      }
    } else {
      stage_tile<128,4>((const u16*)Ag + (long long)tileM * K + kt, K, sA, lane, wave);
    }
    stage_tile<128,4>(Bh_t + kt, K, sB, lane, wave);
    if (SPLIT) stage_tile<128,4>(Bl_t + kt, K, sBl, lane, wave);
    __syncthreads();

    #pragma unroll
    for (int kk=0;kk<2;kk++){
      bf16x8 a[4], b[4], al[4], bl[4];
      #pragma unroll
      for (int i=0;i<4;i++){
        a[i] = ldfrag(sA, wm*64 + i*16, kk, lane);
        b[i] = ldfrag(sB, wn*64 + i*16, kk, lane);
        if (SPLIT){
          al[i] = ldfrag(sAl, wm*64 + i*16, kk, lane);
          bl[i] = ldfrag(sBl, wn*64 + i*16, kk, lane);
        }
      }
      #pragma unroll
      for (int mt=0;mt<4;mt++)
        #pragma unroll
        for (int nt=0;nt<4;nt++){
          acc[mt][nt] = __builtin_amdgcn_mfma_f32_16x16x32_bf16(a[mt], b[nt], acc[mt][nt], 0,0,0);
          if (SPLIT){
            acc[mt][nt] = __builtin_amdgcn_mfma_f32_16x16x32_bf16(al[mt], b[nt],  acc[mt][nt], 0,0,0);
            acc[mt][nt] = __builtin_amdgcn_mfma_f32_16x16x32_bf16(a[mt],  bl[nt], acc[mt][nt], 0,0,0);
          }
        }
    }
    __syncthreads();
  }

  // Epilogue. C/D frag: col = lane&15, row = (lane>>4)*4 + reg  [m89-verified]
  #pragma unroll
  for (int mt=0;mt<4;mt++)
    #pragma unroll
    for (int nt=0;nt<4;nt++){
      const int rl = wm*64 + mt*16 + ((lane >> 4) << 2);
      const int cl = wn*64 + nt*16 + (lane & 15);
      const int gr = tileM + rl;
      const int gc = tileN + cl;
      const float bb = bias ? bias[gc] : 0.f;
      f32x4 v = acc[mt][nt];
      if (WMODE == 0){
        float* o = (float*)Co + (long long)gr * N + gc;
        #pragma unroll
        for (int r=0;r<4;r++) o[(long long)r * N] = v[r] + bb;
      } else if (WMODE == 1){
        u16* o = (u16*)Co + (long long)gr * N + gc;
        #pragma unroll
        for (int r=0;r<4;r++) o[(long long)r * N] = f2bf(v[r] + bb);
      } else {
        const int bidx = gr >> 8, m = gr & 255;       // 4 consecutive m -> 8B store
        const long long off = ((long long)bidx << 16) + ((long long)gc << 8) + m;
        u16x4 h4, l4;
        #pragma unroll
        for (int r=0;r<4;r++){
          float f = v[r] + bb;
          u16 h = f2bf(f);
          h4[r] = h;
          l4[r] = f2bf(f - bf2f(h));
        }
        *(u16x4*)((u16*)Co + off) = h4;
        *(u16x4*)(Cl + off)       = l4;
      }
    }
}

// ---------------------------------------------------------------------------
// k_vkl: fused v-projection + klin.  Reads x once (BM=128 x BN=256, 512 thr).
// Structure mirrors R1's verified k_gemm<1,0,1>: stage -> sync -> MFMA -> sync,
// no cross-iteration prefetch. klin accumulated in fp32 during x staging.
// ---------------------------------------------------------------------------
__global__ __launch_bounds__(512, 2)
void k_vkl(const float* __restrict__ x,
           const u16* __restrict__ Wvh,
           const float* __restrict__ Wk, const float* __restrict__ bk,
           const float* __restrict__ bv,
           u16* __restrict__ vout,
           u16* __restrict__ klTh, u16* __restrict__ klTl)
{
  __shared__ __align__(16) u16 sX[128*64];   // 16KB
  __shared__ __align__(16) u16 sV[256*64];   // 32KB

  const int tid  = threadIdx.x;
  const int lane = tid & 63;
  const int wave = tid >> 6;     // 0..7
  const int wm   = wave >> 2;    // 0..1
  const int wn   = wave & 3;     // 0..3
  const int tileM = blockIdx.x << 7;

  f32x4 acc[4][4];
  #pragma unroll
  for (int i=0;i<4;i++)
    #pragma unroll
    for (int j=0;j<4;j++){
      acc[i][j][0]=0.f; acc[i][j][1]=0.f; acc[i][j][2]=0.f; acc[i][j][3]=0.f;
    }
  float kacc[4] = {0.f, 0.f, 0.f, 0.f};

  for (int kt = 0; kt < 1024; kt += 64){
    // stage x fp32 -> bf16 into sX; accumulate klin partials from fp32 regs
    #pragma unroll
    for (int j=0;j<4;j++){
      int f   = tid + (j << 9);
      int row = f >> 4;
      int c16 = f & 15;
      f32x4 t = *(const f32x4*)(x + (long long)(tileM + row)*1024 + kt + (c16 << 2));
      u16x4 h4;
      #pragma unroll
      for (int e=0;e<4;e++) h4[e] = f2bf(t[e]);
      int off = row*64 + (((c16 >> 1) ^ (row & 7)) << 3) + ((c16 & 1) << 2);
      *(u16x4*)(sX + off) = h4;
      f32x4 w = *(const f32x4*)(Wk + kt + (c16 << 2));
      kacc[j] += t[0]*w[0] + t[1]*w[1] + t[2]*w[2] + t[3]*w[3];
    }
    stage_tile<256,8>(Wvh + kt, 1024, sV, lane, wave);
    __syncthreads();

    #pragma unroll
    for (int kk=0;kk<2;kk++){
      bf16x8 a[4], b[4];
      #pragma unroll
      for (int i=0;i<4;i++){
        a[i] = ldfrag(sX, wm*64 + i*16, kk, lane);
        b[i] = ldfrag(sV, wn*64 + i*16, kk, lane);
      }
      #pragma unroll
      for (int mt=0;mt<4;mt++)
        #pragma unroll
        for (int nt=0;nt<4;nt++)
          acc[mt][nt] = __builtin_amdgcn_mfma_f32_16x16x32_bf16(a[mt], b[nt], acc[mt][nt], 0,0,0);
    }
    __syncthreads();
  }

  // klin: reduce over 16-lane groups (each group owns one row per j), store T
  #pragma unroll
  for (int j=0;j<4;j++){
    #pragma unroll
    for (int m=1;m<16;m<<=1) kacc[j] += __shfl_xor(kacc[j], m, 64);
  }
  if ((lane & 15) == 0){
    #pragma unroll
    for (int j=0;j<4;j++){
      int f = tid + (j << 9);
      int r = tileM + (f >> 4);
      float kv = kacc[j] + bk[0];
      u16 h = f2bf(kv);
      klTh[(r & 255)*256 + (r >> 8)] = h;
      klTl[(r & 255)*256 + (r >> 8)] = f2bf(kv - bf2f(h));
    }
  }

  // epilogue: C/D frag col = lane&15, row = (lane>>4)*4 + reg
  #pragma unroll
  for (int mt=0;mt<4;mt++)
    #pragma unroll
    for (int nt=0;nt<4;nt++){
      const int gr = tileM + wm*64 + mt*16 + ((lane >> 4) << 2);
      const int gc = wn*64 + nt*16 + (lane & 15);
      const float bb = bv[gc];
      u16* o = vout + (long long)gr * 256 + gc;
      f32x4 v = acc[mt][nt];
      #pragma unroll
      for (int r=0;r<4;r++) o[(long long)r * 256] = f2bf(v[r] + bb);
    }
}

// ---------------------------------------------------------------------------
// K3: logits[b,n,:] = sum_m klT[n][m] * qT[b][:,m]  (split 3-pass), then
// row-softmax over qq (full 256 in-block), store attT[b][qq][n] bf16.
// Block = (b, ntile): 64 rows x 256 cols, K=256.
// ---------------------------------------------------------------------------
__global__ __launch_bounds__(256, 1)
void k_logits(const u16* __restrict__ qTh, const u16* __restrict__ qTl,
              const u16* __restrict__ klTh, const u16* __restrict__ klTl,
              u16* __restrict__ attT)
{
  __shared__ __align__(16) union U {
    struct S { u16 Ah[64*64]; u16 Al[64*64]; u16 Bh[256*64]; u16 Bl[256*64]; } s; // 80 KB
    float L[64*260];                                                              // 65 KB
  } u;
  __shared__ float rmax[64], rinv[64];

  const int tid  = threadIdx.x;
  const int lane = tid & 63;
  const int wave = tid >> 6;
  const int bidx  = blockIdx.x >> 2;
  const int ntile = blockIdx.x & 3;

  f32x4 acc[4][4];
  #pragma unroll
  for (int i=0;i<4;i++)
    #pragma unroll
    for (int j=0;j<4;j++){
      acc[i][j][0]=0.f; acc[i][j][1]=0.f; acc[i][j][2]=0.f; acc[i][j][3]=0.f;
    }

  for (int kt=0; kt<256; kt+=64){
    stage_tile<64,4> (klTh + (ntile << 6)*256 + kt, 256, u.s.Ah, lane, wave);
    stage_tile<64,4> (klTl + (ntile << 6)*256 + kt, 256, u.s.Al, lane, wave);
    stage_tile<256,4>(qTh + ((long long)bidx << 16) + kt, 256, u.s.Bh, lane, wave);
    stage_tile<256,4>(qTl + ((long long)bidx << 16) + kt, 256, u.s.Bl, lane, wave);
    __syncthreads();
    #pragma unroll
    for (int kk=0;kk<2;kk++){
      bf16x8 a[4], al[4], b[4], bl[4];
      #pragma unroll
      for (int i=0;i<4;i++){
        a[i]  = ldfrag(u.s.Ah, i*16, kk, lane);
        al[i] = ldfrag(u.s.Al, i*16, kk, lane);
        b[i]  = ldfrag(u.s.Bh, wave*64 + i*16, kk, lane);
        bl[i] = ldfrag(u.s.Bl, wave*64 + i*16, kk, lane);
      }
      #pragma unroll
      for (int mt=0;mt<4;mt++)
        #pragma unroll
        for (int nt=0;nt<4;nt++){
          acc[mt][nt] = __builtin_amdgcn_mfma_f32_16x16x32_bf16(a[mt],  b[nt],  acc[mt][nt], 0,0,0);
          acc[mt][nt] = __builtin_amdgcn_mfma_f32_16x16x32_bf16(al[mt], b[nt],  acc[mt][nt], 0,0,0);
          acc[mt][nt] = __builtin_amdgcn_mfma_f32_16x16x32_bf16(a[mt],  bl[nt], acc[mt][nt], 0,0,0);
        }
    }
    __syncthreads();
  }

  // dump logits (K_DIM=1 => scale 1) into L [64][260]
  #pragma unroll
  for (int mt=0;mt<4;mt++)
    #pragma unroll
    for (int nt=0;nt<4;nt++){
      const int r0 = mt*16 + ((lane >> 4) << 2);
      const int c  = wave*64 + nt*16 + (lane & 15);
      #pragma unroll
      for (int r=0;r<4;r++) u.L[(r0 + r)*260 + c] = acc[mt][nt][r];
    }
  __syncthreads();

  // row max & sum(exp): 4 threads per row
  {
    const int row = tid >> 2, sub = tid & 3;
    const float* Lr = &u.L[row*260 + sub*64];
    float mx = -3.4e38f;
    for (int i=0;i<64;i++) mx = fmaxf(mx, Lr[i]);
    mx = fmaxf(mx, __shfl_xor(mx, 1, 64));
    mx = fmaxf(mx, __shfl_xor(mx, 2, 64));
    float s = 0.f;
    for (int i=0;i<64;i++) s += __expf(Lr[i] - mx);
    s += __shfl_xor(s, 1, 64);
    s += __shfl_xor(s, 2, 64);
    if (sub == 0){ rmax[row] = mx; rinv[row] = 1.f / s; }
  }
  __syncthreads();

  // transposed store: thread qq writes attT[b][qq][ntile*64 .. +64)
  {
    const int qq = tid;
    u16* dst = attT + ((long long)bidx << 16) + qq*256 + (ntile << 6);
    #pragma unroll
    for (int n0=0;n0<64;n0+=8){
      bf16x8 pk;
      #pragma unroll
      for (int e=0;e<8;e++){
        int n = n0 + e;
        float v = __expf(u.L[n*260 + qq] - rmax[n]) * rinv[n];
        pk[e] = (short)f2bf(v);
      }
      *(bf16x8*)(dst + n0) = pk;
    }
  }
}

// split a fp32 array into bf16 hi/lo
__global__ void k_split(const float* __restrict__ w, u16* __restrict__ hi,
                        u16* __restrict__ lo, int n4){
  int i = blockIdx.x * blockDim.x + threadIdx.x;
  if (i >= n4) return;
  f32x4 v = ((const f32x4*)w)[i];
  u16x4 h, l;
  #pragma unroll
  for (int e=0;e<4;e++){
    u16 hh = f2bf(v[e]);
    h[e] = hh;
    l[e] = f2bf(v[e] - bf2f(hh));
  }
  ((u16x4*)hi)[i] = h;
  ((u16x4*)lo)[i] = l;
}

extern "C" void kernel_launch(void* const* d_in, const int* in_sizes, int n_in,
                              void* d_out, int out_size, void* d_ws, size_t ws_size,
                              hipStream_t stream){
  (void)in_sizes; (void)n_in; (void)out_size; (void)ws_size;
  const float* x  = (const float*)d_in[0];
  const float* Wq = (const float*)d_in[1];
  const float* bq = (const float*)d_in[2];
  const float* Wk = (const float*)d_in[3];
  const float* bk = (const float*)d_in[4];
  const float* Wv = (const float*)d_in[5];
  const float* bv = (const float*)d_in[6];
  const float* Wo = (const float*)d_in[7];
  const float* bo = (const float*)d_in[8];

  // scratch carved from d_out (dead before K5 rewrites it) + d_ws
  char* ob = (char*)d_out;
  u16* qTh  = (u16*)(ob);                          // 33.5 MB
  u16* qTl  = (u16*)(ob + (size_t)33554432);       // 33.5 MB
  u16* vh   = (u16*)(ob + (size_t)67108864);       // 33.5 MB
  u16* attT = (u16*)(ob + (size_t)100663296);      // 33.5 MB
  char* wb = (char*)d_ws;
  u16* omh  = (u16*)(wb);                          // 33.5 MB
  u16* Wqh  = (u16*)(wb + (size_t)33554432);
  u16* Wql  = Wqh + 262144;
  u16* Wvh  = Wql + 262144;
  u16* Wvl  = Wvh + 262144;
  u16* Woh  = Wvl + 262144;
  u16* Wol  = Woh + 262144;
  u16* klTh = Wol + 262144;                        // 128 KB
  u16* klTl = klTh + 65536;                        // total ws ~36.9 MB

  k_split<<<256, 256, 0, stream>>>(Wq, Wqh, Wql, 65536);
  k_split<<<256, 256, 0, stream>>>(Wv, Wvh, Wvl, 65536);
  k_split<<<256, 256, 0, stream>>>(Wo, Woh, Wol, 65536);

  // K1: qT (split, transposed bf16-pair out), N=256, K=1024  [R1-proven]
  k_gemm<1,1,2><<<1024, 256, 0, stream>>>(x, Wqh, Wql, 256, 1024, 2, 0, bq, qTh, qTl);
  // fused v + klin (reads x once)
  k_vkl<<<512, 512, 0, stream>>>(x, Wvh, Wk, bk, bv, vh, klTh, klTl);
  // K3: logits + softmax -> attT
  k_logits<<<1024, 256, 0, stream>>>(qTh, qTl, klTh, klTl, attT);
  // K4: om = v @ att (B batched per b), N=256, K=256
  k_gemm<0,0,1><<<1024, 256, 0, stream>>>(vh, attT, nullptr, 256, 256, 2, 65536, nullptr, omh, nullptr);
  // K5: out = om @ Wo^T + bo (fp32 out), N=1024, K=256
  k_gemm<0,0,0><<<4096, 256, 0, stream>>>(omh, Woh, nullptr, 1024, 256, 8, 0, bo, d_out, nullptr);
}

// Round 4
// 404.661 us; speedup vs baseline: 1.2451x; 1.0478x over previous
//
#include <hip/hip_runtime.h>

// ---------------------------------------------------------------------------
// Self_Attention_30193620091602  (N=256, A=1024, K_DIM=1), fp32 in/out.
// R4: k_qvkl fuses q-projection (split-bf16 3-pass), v-projection, and klin
// into ONE kernel that reads x exactly once. Built as R3's proven k_vkl
// skeleton (2-barrier loop, direct x loads, NO cross-iteration prefetch —
// the R2-unique structure suspected for the R2 precision failure) plus
// verbatim splices of R1's proven SPLIT staging/MFMA/epilogue.
// K3 (logits+softmax), K4 (PV), K5 (out-proj) unchanged (R1/R3-proven).
// Scratch: d_out[0..134MB) holds qT/v/attT (dead before K5 overwrites d_out);
// d_ws holds om + split weights + klT (~37 MB).
// ---------------------------------------------------------------------------

typedef unsigned short u16;
typedef unsigned int   uint;
using f32x4  = __attribute__((ext_vector_type(4))) float;
using bf16x8 = __attribute__((ext_vector_type(8))) short;
using u16x4  = __attribute__((ext_vector_type(4))) u16;

#define DEVI static __device__ __forceinline__

DEVI u16 f2bf(float f){
  union { float f; uint u; } v; v.f = f;
  uint r = v.u + 0x7fffu + ((v.u >> 16) & 1u);   // round-to-nearest-even
  return (u16)(r >> 16);
}
DEVI float bf2f(u16 h){
  union { uint u; float f; } v; v.u = ((uint)h) << 16;
  return v.f;
}

typedef const uint __attribute__((address_space(1)))* as1_cuintp;
typedef uint __attribute__((address_space(3)))* as3_uintp;

DEVI void gl_lds16(const void* g, void* l){
  __builtin_amdgcn_global_load_lds((as1_cuintp)g, (as3_uintp)l, 16, 0, 0);
}

// Stage ROWS x 64 bf16 tile (rowStride elems in global) into LDS, NW waves.
// LDS layout: elem(row,k) at row*64 + ((k/8 ^ (row&7))*8 + k%8)  (16B-chunk
// XOR swizzle; global_load_lds writes linearly, so the SOURCE is pre-swizzled).
template<int ROWS, int NW>
DEVI void stage_tile(const u16* __restrict__ g, long long rowStride,
                     u16* lds, int lane, int wave){
  constexpr int NLD = ROWS >> 3;            // 1KB wave-loads
  #pragma unroll
  for (int j = 0; j < NLD/NW; ++j){
    int r0  = (wave + NW*j) << 3;
    int row = r0 + (lane >> 3);
    const u16* src = g + (long long)row * rowStride
                       + (((lane & 7) ^ (lane >> 3)) << 3);
    gl_lds16(src, lds + r0 * 64);
  }
}

// MFMA A/B fragment read from the swizzled [*,64] LDS tile.
DEVI bf16x8 ldfrag(const u16* s, int rbase, int kk, int lane){
  int row = rbase + (lane & 15);
  int c   = (kk << 2) + (lane >> 4);
  return *(const bf16x8*)(s + row*64 + ((c ^ (row & 7)) << 3));
}

// ---------------------------------------------------------------------------
// k_qvkl: fused q(split) + v + klin.  Reads x once (BM=128 x N=256, 512 thr,
// 8 waves as 2(wm) x 4(wn)).  R3-proven 2-barrier loop, direct x loads.
// ---------------------------------------------------------------------------
__global__ __launch_bounds__(512, 2)
void k_qvkl(const float* __restrict__ x,
            const u16* __restrict__ Wqh, const u16* __restrict__ Wql,
            const u16* __restrict__ Wvh,
            const float* __restrict__ Wk, const float* __restrict__ bk,
            const float* __restrict__ bq, const float* __restrict__ bv,
            u16* __restrict__ qTh, u16* __restrict__ qTl,
            u16* __restrict__ vout,
            u16* __restrict__ klTh, u16* __restrict__ klTl)
{
  __shared__ __align__(16) u16 sX [128*64];   // 16KB
  __shared__ __align__(16) u16 sXl[128*64];   // 16KB
  __shared__ __align__(16) u16 sQh[256*64];   // 32KB
  __shared__ __align__(16) u16 sQl[256*64];   // 32KB
  __shared__ __align__(16) u16 sV [256*64];   // 32KB  -> 128KB total

  const int tid  = threadIdx.x;
  const int lane = tid & 63;
  const int wave = tid >> 6;     // 0..7
  const int wm   = wave >> 2;    // 0..1
  const int wn   = wave & 3;     // 0..3
  const int tileM = blockIdx.x << 7;

  f32x4 qacc[4][4], vacc[4][4];
  #pragma unroll
  for (int i=0;i<4;i++)
    #pragma unroll
    for (int j=0;j<4;j++){
      qacc[i][j][0]=0.f; qacc[i][j][1]=0.f; qacc[i][j][2]=0.f; qacc[i][j][3]=0.f;
      vacc[i][j][0]=0.f; vacc[i][j][1]=0.f; vacc[i][j][2]=0.f; vacc[i][j][3]=0.f;
    }
  float kacc[4] = {0.f, 0.f, 0.f, 0.f};

  for (int kt = 0; kt < 1024; kt += 64){
    // stage x fp32 -> bf16 hi/lo into sX/sXl; accumulate klin from fp32 regs
    // (verbatim R1 AF32-SPLIT staging, 512-thread indexing as in R3 k_vkl)
    #pragma unroll
    for (int j=0;j<4;j++){
      int f   = tid + (j << 9);
      int row = f >> 4;
      int c16 = f & 15;
      f32x4 t = *(const f32x4*)(x + (long long)(tileM + row)*1024 + kt + (c16 << 2));
      u16x4 h4, l4;
      #pragma unroll
      for (int e=0;e<4;e++){
        u16 h = f2bf(t[e]);
        h4[e] = h;
        l4[e] = f2bf(t[e] - bf2f(h));
      }
      int off = row*64 + (((c16 >> 1) ^ (row & 7)) << 3) + ((c16 & 1) << 2);
      *(u16x4*)(sX  + off) = h4;
      *(u16x4*)(sXl + off) = l4;
      f32x4 w = *(const f32x4*)(Wk + kt + (c16 << 2));
      kacc[j] += t[0]*w[0] + t[1]*w[1] + t[2]*w[2] + t[3]*w[3];
    }
    stage_tile<256,8>(Wqh + kt, 1024, sQh, lane, wave);
    stage_tile<256,8>(Wql + kt, 1024, sQl, lane, wave);
    stage_tile<256,8>(Wvh + kt, 1024, sV , lane, wave);
    __syncthreads();

    #pragma unroll
    for (int kk=0;kk<2;kk++){
      bf16x8 a[4], al[4];
      #pragma unroll
      for (int i=0;i<4;i++){
        a[i]  = ldfrag(sX , wm*64 + i*16, kk, lane);
        al[i] = ldfrag(sXl, wm*64 + i*16, kk, lane);
      }
      {
        bf16x8 b[4];
        #pragma unroll
        for (int i=0;i<4;i++) b[i] = ldfrag(sQh, wn*64 + i*16, kk, lane);
        #pragma unroll
        for (int mt=0;mt<4;mt++)
          #pragma unroll
          for (int nt=0;nt<4;nt++){
            qacc[mt][nt] = __builtin_amdgcn_mfma_f32_16x16x32_bf16(a[mt],  b[nt], qacc[mt][nt], 0,0,0);
            qacc[mt][nt] = __builtin_amdgcn_mfma_f32_16x16x32_bf16(al[mt], b[nt], qacc[mt][nt], 0,0,0);
          }
      }
      {
        bf16x8 b[4];
        #pragma unroll
        for (int i=0;i<4;i++) b[i] = ldfrag(sQl, wn*64 + i*16, kk, lane);
        #pragma unroll
        for (int mt=0;mt<4;mt++)
          #pragma unroll
          for (int nt=0;nt<4;nt++)
            qacc[mt][nt] = __builtin_amdgcn_mfma_f32_16x16x32_bf16(a[mt], b[nt], qacc[mt][nt], 0,0,0);
      }
      {
        bf16x8 b[4];
        #pragma unroll
        for (int i=0;i<4;i++) b[i] = ldfrag(sV, wn*64 + i*16, kk, lane);
        #pragma unroll
        for (int mt=0;mt<4;mt++)
          #pragma unroll
          for (int nt=0;nt<4;nt++)
            vacc[mt][nt] = __builtin_amdgcn_mfma_f32_16x16x32_bf16(a[mt], b[nt], vacc[mt][nt], 0,0,0);
      }
    }
    __syncthreads();
  }

  // klin: reduce over 16-lane groups (each group owns one row per j), store T
  #pragma unroll
  for (int j=0;j<4;j++){
    #pragma unroll
    for (int m=1;m<16;m<<=1) kacc[j] += __shfl_xor(kacc[j], m, 64);
  }
  if ((lane & 15) == 0){
    #pragma unroll
    for (int j=0;j<4;j++){
      int f = tid + (j << 9);
      int r = tileM + (f >> 4);
      float kv = kacc[j] + bk[0];
      u16 h = f2bf(kv);
      klTh[(r & 255)*256 + (r >> 8)] = h;
      klTl[(r & 255)*256 + (r >> 8)] = f2bf(kv - bf2f(h));
    }
  }

  // epilogue: C/D frag col = lane&15, row = (lane>>4)*4 + reg
  #pragma unroll
  for (int mt=0;mt<4;mt++)
    #pragma unroll
    for (int nt=0;nt<4;nt++){
      const int gr = tileM + wm*64 + mt*16 + ((lane >> 4) << 2);
      const int gc = wn*64 + nt*16 + (lane & 15);
      // qT: transposed hi/lo pair, 4 consecutive m -> 8B store (R1 WMODE=2)
      {
        const int bidx = gr >> 8, m = gr & 255;
        const long long off = ((long long)bidx << 16) + ((long long)gc << 8) + m;
        const float bb = bq[gc];
        u16x4 h4, l4;
        f32x4 v = qacc[mt][nt];
        #pragma unroll
        for (int r=0;r<4;r++){
          float fq = v[r] + bb;
          u16 h = f2bf(fq);
          h4[r] = h;
          l4[r] = f2bf(fq - bf2f(h));
        }
        *(u16x4*)(qTh + off) = h4;
        *(u16x4*)(qTl + off) = l4;
      }
      // v: natural bf16 (R1 WMODE=1)
      {
        const float bb = bv[gc];
        u16* o = vout + (long long)gr * 256 + gc;
        f32x4 v = vacc[mt][nt];
        #pragma unroll
        for (int r=0;r<4;r++) o[(long long)r * 256] = f2bf(v[r] + bb);
      }
    }
}

// ---------------------------------------------------------------------------
// Generic GEMM: C[M x N] = A[M x K] * B^T (B stored N x K) (+bias)
// WMODE: 0 = fp32 natural (+bias)   (out-proj)
//        1 = bf16 natural (+bias)   (om)
// bStrideB: if nonzero, B is batched per b = row/256 (attT).
// ---------------------------------------------------------------------------
template<int WMODE>
__global__ __launch_bounds__(256, 2)
void k_gemm(const u16* __restrict__ Ag,
            const u16* __restrict__ Bhg,
            int N, int K, int tnCount, long long bStrideB,
            const float* __restrict__ bias,
            void* __restrict__ Co)
{
  __shared__ __align__(16) u16 sA[128*64];
  __shared__ __align__(16) u16 sB[128*64];

  const int tid  = threadIdx.x;
  const int lane = tid & 63;
  const int wave = tid >> 6;
  const int wm   = wave >> 1;
  const int wn   = wave & 1;
  const int tn   = blockIdx.x % tnCount;
  const int tm   = blockIdx.x / tnCount;
  const int tileM = tm << 7;
  const int tileN = tn << 7;

  const long long bOff = bStrideB ? (long long)(tileM >> 8) * bStrideB : 0;
  const u16* Bh_t = Bhg + bOff + (long long)tileN * K;

  f32x4 acc[4][4];
  #pragma unroll
  for (int i=0;i<4;i++)
    #pragma unroll
    for (int j=0;j<4;j++){
      acc[i][j][0]=0.f; acc[i][j][1]=0.f; acc[i][j][2]=0.f; acc[i][j][3]=0.f;
    }

  for (int kt = 0; kt < K; kt += 64){
    stage_tile<128,4>(Ag + (long long)tileM * K + kt, K, sA, lane, wave);
    stage_tile<128,4>(Bh_t + kt, K, sB, lane, wave);
    __syncthreads();
    #pragma unroll
    for (int kk=0;kk<2;kk++){
      bf16x8 a[4], b[4];
      #pragma unroll
      for (int i=0;i<4;i++){
        a[i] = ldfrag(sA, wm*64 + i*16, kk, lane);
        b[i] = ldfrag(sB, wn*64 + i*16, kk, lane);
      }
      #pragma unroll
      for (int mt=0;mt<4;mt++)
        #pragma unroll
        for (int nt=0;nt<4;nt++)
          acc[mt][nt] = __builtin_amdgcn_mfma_f32_16x16x32_bf16(a[mt], b[nt], acc[mt][nt], 0,0,0);
    }
    __syncthreads();
  }

  #pragma unroll
  for (int mt=0;mt<4;mt++)
    #pragma unroll
    for (int nt=0;nt<4;nt++){
      const int gr = tileM + wm*64 + mt*16 + ((lane >> 4) << 2);
      const int gc = tileN + wn*64 + nt*16 + (lane & 15);
      const float bb = bias ? bias[gc] : 0.f;
      f32x4 v = acc[mt][nt];
      if (WMODE == 0){
        float* o = (float*)Co + (long long)gr * N + gc;
        #pragma unroll
        for (int r=0;r<4;r++) o[(long long)r * N] = v[r] + bb;
      } else {
        u16* o = (u16*)Co + (long long)gr * N + gc;
        #pragma unroll
        for (int r=0;r<4;r++) o[(long long)r * N] = f2bf(v[r] + bb);
      }
    }
}

// ---------------------------------------------------------------------------
// K3: logits[b,n,:] = sum_m klT[n][m] * qT[b][:,m]  (split 3-pass), then
// row-softmax over qq (full 256 in-block), store attT[b][qq][n] bf16.
// Block = (b, ntile): 64 rows x 256 cols, K=256.
// ---------------------------------------------------------------------------
__global__ __launch_bounds__(256, 1)
void k_logits(const u16* __restrict__ qTh, const u16* __restrict__ qTl,
              const u16* __restrict__ klTh, const u16* __restrict__ klTl,
              u16* __restrict__ attT)
{
  __shared__ __align__(16) union U {
    struct S { u16 Ah[64*64]; u16 Al[64*64]; u16 Bh[256*64]; u16 Bl[256*64]; } s; // 80 KB
    float L[64*260];                                                              // 65 KB
  } u;
  __shared__ float rmax[64], rinv[64];

  const int tid  = threadIdx.x;
  const int lane = tid & 63;
  const int wave = tid >> 6;
  const int bidx  = blockIdx.x >> 2;
  const int ntile = blockIdx.x & 3;

  f32x4 acc[4][4];
  #pragma unroll
  for (int i=0;i<4;i++)
    #pragma unroll
    for (int j=0;j<4;j++){
      acc[i][j][0]=0.f; acc[i][j][1]=0.f; acc[i][j][2]=0.f; acc[i][j][3]=0.f;
    }

  for (int kt=0; kt<256; kt+=64){
    stage_tile<64,4> (klTh + (ntile << 6)*256 + kt, 256, u.s.Ah, lane, wave);
    stage_tile<64,4> (klTl + (ntile << 6)*256 + kt, 256, u.s.Al, lane, wave);
    stage_tile<256,4>(qTh + ((long long)bidx << 16) + kt, 256, u.s.Bh, lane, wave);
    stage_tile<256,4>(qTl + ((long long)bidx << 16) + kt, 256, u.s.Bl, lane, wave);
    __syncthreads();
    #pragma unroll
    for (int kk=0;kk<2;kk++){
      bf16x8 a[4], al[4], b[4], bl[4];
      #pragma unroll
      for (int i=0;i<4;i++){
        a[i]  = ldfrag(u.s.Ah, i*16, kk, lane);
        al[i] = ldfrag(u.s.Al, i*16, kk, lane);
        b[i]  = ldfrag(u.s.Bh, wave*64 + i*16, kk, lane);
        bl[i] = ldfrag(u.s.Bl, wave*64 + i*16, kk, lane);
      }
      #pragma unroll
      for (int mt=0;mt<4;mt++)
        #pragma unroll
        for (int nt=0;nt<4;nt++){
          acc[mt][nt] = __builtin_amdgcn_mfma_f32_16x16x32_bf16(a[mt],  b[nt],  acc[mt][nt], 0,0,0);
          acc[mt][nt] = __builtin_amdgcn_mfma_f32_16x16x32_bf16(al[mt], b[nt],  acc[mt][nt], 0,0,0);
          acc[mt][nt] = __builtin_amdgcn_mfma_f32_16x16x32_bf16(a[mt],  bl[nt], acc[mt][nt], 0,0,0);
        }
    }
    __syncthreads();
  }

  // dump logits (K_DIM=1 => scale 1) into L [64][260]
  #pragma unroll
  for (int mt=0;mt<4;mt++)
    #pragma unroll
    for (int nt=0;nt<4;nt++){
      const int r0 = mt*16 + ((lane >> 4) << 2);
      const int c  = wave*64 + nt*16 + (lane & 15);
      #pragma unroll
      for (int r=0;r<4;r++) u.L[(r0 + r)*260 + c] = acc[mt][nt][r];
    }
  __syncthreads();

  // row max & sum(exp): 4 threads per row
  {
    const int row = tid >> 2, sub = tid & 3;
    const float* Lr = &u.L[row*260 + sub*64];
    float mx = -3.4e38f;
    for (int i=0;i<64;i++) mx = fmaxf(mx, Lr[i]);
    mx = fmaxf(mx, __shfl_xor(mx, 1, 64));
    mx = fmaxf(mx, __shfl_xor(mx, 2, 64));
    float s = 0.f;
    for (int i=0;i<64;i++) s += __expf(Lr[i] - mx);
    s += __shfl_xor(s, 1, 64);
    s += __shfl_xor(s, 2, 64);
    if (sub == 0){ rmax[row] = mx; rinv[row] = 1.f / s; }
  }
  __syncthreads();

  // transposed store: thread qq writes attT[b][qq][ntile*64 .. +64)
  {
    const int qq = tid;
    u16* dst = attT + ((long long)bidx << 16) + qq*256 + (ntile << 6);
    #pragma unroll
    for (int n0=0;n0<64;n0+=8){
      bf16x8 pk;
      #pragma unroll
      for (int e=0;e<8;e++){
        int n = n0 + e;
        float v = __expf(u.L[n*260 + qq] - rmax[n]) * rinv[n];
        pk[e] = (short)f2bf(v);
      }
      *(bf16x8*)(dst + n0) = pk;
    }
  }
}

// split a fp32 array into bf16 hi/lo
__global__ void k_split(const float* __restrict__ w, u16* __restrict__ hi,
                        u16* __restrict__ lo, int n4){
  int i = blockIdx.x * blockDim.x + threadIdx.x;
  if (i >= n4) return;
  f32x4 v = ((const f32x4*)w)[i];
  u16x4 h, l;
  #pragma unroll
  for (int e=0;e<4;e++){
    u16 hh = f2bf(v[e]);
    h[e] = hh;
    l[e] = f2bf(v[e] - bf2f(hh));
  }
  ((u16x4*)hi)[i] = h;
  ((u16x4*)lo)[i] = l;
}

extern "C" void kernel_launch(void* const* d_in, const int* in_sizes, int n_in,
                              void* d_out, int out_size, void* d_ws, size_t ws_size,
                              hipStream_t stream){
  (void)in_sizes; (void)n_in; (void)out_size; (void)ws_size;
  const float* x  = (const float*)d_in[0];
  const float* Wq = (const float*)d_in[1];
  const float* bq = (const float*)d_in[2];
  const float* Wk = (const float*)d_in[3];
  const float* bk = (const float*)d_in[4];
  const float* Wv = (const float*)d_in[5];
  const float* bv = (const float*)d_in[6];
  const float* Wo = (const float*)d_in[7];
  const float* bo = (const float*)d_in[8];

  // scratch carved from d_out (dead before K5 rewrites it) + d_ws
  char* ob = (char*)d_out;
  u16* qTh  = (u16*)(ob);                          // 33.5 MB
  u16* qTl  = (u16*)(ob + (size_t)33554432);       // 33.5 MB
  u16* vh   = (u16*)(ob + (size_t)67108864);       // 33.5 MB
  u16* attT = (u16*)(ob + (size_t)100663296);      // 33.5 MB
  char* wb = (char*)d_ws;
  u16* omh  = (u16*)(wb);                          // 33.5 MB
  u16* Wqh  = (u16*)(wb + (size_t)33554432);
  u16* Wql  = Wqh + 262144;
  u16* Wvh  = Wql + 262144;
  u16* Wvl  = Wvh + 262144;
  u16* Woh  = Wvl + 262144;
  u16* Wol  = Woh + 262144;
  u16* klTh = Wol + 262144;                        // 128 KB
  u16* klTl = klTh + 65536;                        // total ws ~36.9 MB

  k_split<<<256, 256, 0, stream>>>(Wq, Wqh, Wql, 65536);
  k_split<<<256, 256, 0, stream>>>(Wv, Wvh, Wvl, 65536);
  k_split<<<256, 256, 0, stream>>>(Wo, Woh, Wol, 65536);

  // fused q(split)/v/klin: reads x once
  k_qvkl<<<512, 512, 0, stream>>>(x, Wqh, Wql, Wvh, Wk, bk, bq, bv,
                                  qTh, qTl, vh, klTh, klTl);
  // K3: logits + softmax -> attT
  k_logits<<<1024, 256, 0, stream>>>(qTh, qTl, klTh, klTl, attT);
  // K4: om = v @ att (B batched per b), N=256, K=256
  k_gemm<1><<<1024, 256, 0, stream>>>(vh, attT, 256, 256, 2, 65536, nullptr, omh);
  // K5: out = om @ Wo^T + bo (fp32 out), N=1024, K=256
  k_gemm<0><<<4096, 256, 0, stream>>>(omh, Woh, 1024, 256, 8, 0, bo, d_out);
}

// Round 5
// 354.376 us; speedup vs baseline: 1.4218x; 1.1419x over previous
//
#include <hip/hip_runtime.h>

// ---------------------------------------------------------------------------
// Self_Attention_30193620091602  (N=256, A=1024, K_DIM=1), fp32 in/out.
// R5: R4's verified k_qvkl + x register prefetch (T14 issue-early/consume-
// late): step t+1's x loads are issued right after the LDS-publish barrier,
// so they are in flight during step t's 128-MFMA phase instead of stalling
// ~900cy at consume (R4 measured 1.2 TB/s Little's-law limit, 255us).
// This also completes the R2 bisection (R2 = this + weights-before-x order).
// K3 (logits+softmax), K4 (PV), K5 (out-proj) unchanged (R1/R3-proven).
// Scratch: d_out[0..134MB) holds qT/v/attT (dead before K5 overwrites d_out);
// d_ws holds om + split weights + klT (~37 MB).
// ---------------------------------------------------------------------------

typedef unsigned short u16;
typedef unsigned int   uint;
using f32x4  = __attribute__((ext_vector_type(4))) float;
using bf16x8 = __attribute__((ext_vector_type(8))) short;
using u16x4  = __attribute__((ext_vector_type(4))) u16;

#define DEVI static __device__ __forceinline__

DEVI u16 f2bf(float f){
  union { float f; uint u; } v; v.f = f;
  uint r = v.u + 0x7fffu + ((v.u >> 16) & 1u);   // round-to-nearest-even
  return (u16)(r >> 16);
}
DEVI float bf2f(u16 h){
  union { uint u; float f; } v; v.u = ((uint)h) << 16;
  return v.f;
}

typedef const uint __attribute__((address_space(1)))* as1_cuintp;
typedef uint __attribute__((address_space(3)))* as3_uintp;

DEVI void gl_lds16(const void* g, void* l){
  __builtin_amdgcn_global_load_lds((as1_cuintp)g, (as3_uintp)l, 16, 0, 0);
}

// Stage ROWS x 64 bf16 tile (rowStride elems in global) into LDS, NW waves.
// LDS layout: elem(row,k) at row*64 + ((k/8 ^ (row&7))*8 + k%8)  (16B-chunk
// XOR swizzle; global_load_lds writes linearly, so the SOURCE is pre-swizzled).
template<int ROWS, int NW>
DEVI void stage_tile(const u16* __restrict__ g, long long rowStride,
                     u16* lds, int lane, int wave){
  constexpr int NLD = ROWS >> 3;            // 1KB wave-loads
  #pragma unroll
  for (int j = 0; j < NLD/NW; ++j){
    int r0  = (wave + NW*j) << 3;
    int row = r0 + (lane >> 3);
    const u16* src = g + (long long)row * rowStride
                       + (((lane & 7) ^ (lane >> 3)) << 3);
    gl_lds16(src, lds + r0 * 64);
  }
}

// MFMA A/B fragment read from the swizzled [*,64] LDS tile.
DEVI bf16x8 ldfrag(const u16* s, int rbase, int kk, int lane){
  int row = rbase + (lane & 15);
  int c   = (kk << 2) + (lane >> 4);
  return *(const bf16x8*)(s + row*64 + ((c ^ (row & 7)) << 3));
}

// ---------------------------------------------------------------------------
// k_qvkl: fused q(split) + v + klin.  Reads x once (BM=128 x N=256, 512 thr,
// 8 waves as 2(wm) x 4(wn)).  R4 structure + x register prefetch.
// ---------------------------------------------------------------------------
__global__ __launch_bounds__(512, 2)
void k_qvkl(const float* __restrict__ x,
            const u16* __restrict__ Wqh, const u16* __restrict__ Wql,
            const u16* __restrict__ Wvh,
            const float* __restrict__ Wk, const float* __restrict__ bk,
            const float* __restrict__ bq, const float* __restrict__ bv,
            u16* __restrict__ qTh, u16* __restrict__ qTl,
            u16* __restrict__ vout,
            u16* __restrict__ klTh, u16* __restrict__ klTl)
{
  __shared__ __align__(16) u16 sX [128*64];   // 16KB
  __shared__ __align__(16) u16 sXl[128*64];   // 16KB
  __shared__ __align__(16) u16 sQh[256*64];   // 32KB
  __shared__ __align__(16) u16 sQl[256*64];   // 32KB
  __shared__ __align__(16) u16 sV [256*64];   // 32KB  -> 128KB total

  const int tid  = threadIdx.x;
  const int lane = tid & 63;
  const int wave = tid >> 6;     // 0..7
  const int wm   = wave >> 2;    // 0..1
  const int wn   = wave & 3;     // 0..3
  const int tileM = blockIdx.x << 7;

  f32x4 qacc[4][4], vacc[4][4];
  #pragma unroll
  for (int i=0;i<4;i++)
    #pragma unroll
    for (int j=0;j<4;j++){
      qacc[i][j][0]=0.f; qacc[i][j][1]=0.f; qacc[i][j][2]=0.f; qacc[i][j][3]=0.f;
      vacc[i][j][0]=0.f; vacc[i][j][1]=0.f; vacc[i][j][2]=0.f; vacc[i][j][3]=0.f;
    }
  float kacc[4] = {0.f, 0.f, 0.f, 0.f};

  // prologue: x registers for step 0  (flat f32x4 id f = tid + 512j)
  f32x4 xr[4];
  #pragma unroll
  for (int j=0;j<4;j++){
    int f = tid + (j << 9);
    xr[j] = *(const f32x4*)(x + (long long)(tileM + (f >> 4))*1024 + ((f & 15) << 2));
  }

  for (int kt = 0; kt < 1024; kt += 64){
    // convert this step's x (already in regs) -> bf16 hi/lo into sX/sXl;
    // accumulate klin from fp32 regs  (verbatim R4 math)
    #pragma unroll
    for (int j=0;j<4;j++){
      int f   = tid + (j << 9);
      int row = f >> 4;
      int c16 = f & 15;
      f32x4 t = xr[j];
      u16x4 h4, l4;
      #pragma unroll
      for (int e=0;e<4;e++){
        u16 h = f2bf(t[e]);
        h4[e] = h;
        l4[e] = f2bf(t[e] - bf2f(h));
      }
      int off = row*64 + (((c16 >> 1) ^ (row & 7)) << 3) + ((c16 & 1) << 2);
      *(u16x4*)(sX  + off) = h4;
      *(u16x4*)(sXl + off) = l4;
      f32x4 w = *(const f32x4*)(Wk + kt + (c16 << 2));
      kacc[j] += t[0]*w[0] + t[1]*w[1] + t[2]*w[2] + t[3]*w[3];
    }
    stage_tile<256,8>(Wqh + kt, 1024, sQh, lane, wave);
    stage_tile<256,8>(Wql + kt, 1024, sQl, lane, wave);
    stage_tile<256,8>(Wvh + kt, 1024, sV , lane, wave);
    __syncthreads();   // B1: publishes this step's LDS

    // prefetch next step's x; in flight during the MFMA phase below,
    // drained by B2's implicit vmcnt(0) after ~1280cy of MFMA cover.
    if (kt < 960){
      #pragma unroll
      for (int j=0;j<4;j++){
        int f = tid + (j << 9);
        xr[j] = *(const f32x4*)(x + (long long)(tileM + (f >> 4))*1024
                                + (kt + 64) + ((f & 15) << 2));
      }
    }

    #pragma unroll
    for (int kk=0;kk<2;kk++){
      bf16x8 a[4], al[4];
      #pragma unroll
      for (int i=0;i<4;i++){
        a[i]  = ldfrag(sX , wm*64 + i*16, kk, lane);
        al[i] = ldfrag(sXl, wm*64 + i*16, kk, lane);
      }
      {
        bf16x8 b[4];
        #pragma unroll
        for (int i=0;i<4;i++) b[i] = ldfrag(sQh, wn*64 + i*16, kk, lane);
        #pragma unroll
        for (int mt=0;mt<4;mt++)
          #pragma unroll
          for (int nt=0;nt<4;nt++){
            qacc[mt][nt] = __builtin_amdgcn_mfma_f32_16x16x32_bf16(a[mt],  b[nt], qacc[mt][nt], 0,0,0);
            qacc[mt][nt] = __builtin_amdgcn_mfma_f32_16x16x32_bf16(al[mt], b[nt], qacc[mt][nt], 0,0,0);
          }
      }
      {
        bf16x8 b[4];
        #pragma unroll
        for (int i=0;i<4;i++) b[i] = ldfrag(sQl, wn*64 + i*16, kk, lane);
        #pragma unroll
        for (int mt=0;mt<4;mt++)
          #pragma unroll
          for (int nt=0;nt<4;nt++)
            qacc[mt][nt] = __builtin_amdgcn_mfma_f32_16x16x32_bf16(a[mt], b[nt], qacc[mt][nt], 0,0,0);
      }
      {
        bf16x8 b[4];
        #pragma unroll
        for (int i=0;i<4;i++) b[i] = ldfrag(sV, wn*64 + i*16, kk, lane);
        #pragma unroll
        for (int mt=0;mt<4;mt++)
          #pragma unroll
          for (int nt=0;nt<4;nt++)
            vacc[mt][nt] = __builtin_amdgcn_mfma_f32_16x16x32_bf16(a[mt], b[nt], vacc[mt][nt], 0,0,0);
      }
    }
    __syncthreads();   // B2: LDS reads done; prefetch loads drained
  }

  // klin: reduce over 16-lane groups (each group owns one row per j), store T
  #pragma unroll
  for (int j=0;j<4;j++){
    #pragma unroll
    for (int m=1;m<16;m<<=1) kacc[j] += __shfl_xor(kacc[j], m, 64);
  }
  if ((lane & 15) == 0){
    #pragma unroll
    for (int j=0;j<4;j++){
      int f = tid + (j << 9);
      int r = tileM + (f >> 4);
      float kv = kacc[j] + bk[0];
      u16 h = f2bf(kv);
      klTh[(r & 255)*256 + (r >> 8)] = h;
      klTl[(r & 255)*256 + (r >> 8)] = f2bf(kv - bf2f(h));
    }
  }

  // epilogue: C/D frag col = lane&15, row = (lane>>4)*4 + reg
  #pragma unroll
  for (int mt=0;mt<4;mt++)
    #pragma unroll
    for (int nt=0;nt<4;nt++){
      const int gr = tileM + wm*64 + mt*16 + ((lane >> 4) << 2);
      const int gc = wn*64 + nt*16 + (lane & 15);
      // qT: transposed hi/lo pair, 4 consecutive m -> 8B store (R1 WMODE=2)
      {
        const int bidx = gr >> 8, m = gr & 255;
        const long long off = ((long long)bidx << 16) + ((long long)gc << 8) + m;
        const float bb = bq[gc];
        u16x4 h4, l4;
        f32x4 v = qacc[mt][nt];
        #pragma unroll
        for (int r=0;r<4;r++){
          float fq = v[r] + bb;
          u16 h = f2bf(fq);
          h4[r] = h;
          l4[r] = f2bf(fq - bf2f(h));
        }
        *(u16x4*)(qTh + off) = h4;
        *(u16x4*)(qTl + off) = l4;
      }
      // v: natural bf16 (R1 WMODE=1)
      {
        const float bb = bv[gc];
        u16* o = vout + (long long)gr * 256 + gc;
        f32x4 v = vacc[mt][nt];
        #pragma unroll
        for (int r=0;r<4;r++) o[(long long)r * 256] = f2bf(v[r] + bb);
      }
    }
}

// ---------------------------------------------------------------------------
// Generic GEMM: C[M x N] = A[M x K] * B^T (B stored N x K) (+bias)
// WMODE: 0 = fp32 natural (+bias)   (out-proj)
//        1 = bf16 natural (+bias)   (om)
// bStrideB: if nonzero, B is batched per b = row/256 (attT).
// ---------------------------------------------------------------------------
template<int WMODE>
__global__ __launch_bounds__(256, 2)
void k_gemm(const u16* __restrict__ Ag,
            const u16* __restrict__ Bhg,
            int N, int K, int tnCount, long long bStrideB,
            const float* __restrict__ bias,
            void* __restrict__ Co)
{
  __shared__ __align__(16) u16 sA[128*64];
  __shared__ __align__(16) u16 sB[128*64];

  const int tid  = threadIdx.x;
  const int lane = tid & 63;
  const int wave = tid >> 6;
  const int wm   = wave >> 1;
  const int wn   = wave & 1;
  const int tn   = blockIdx.x % tnCount;
  const int tm   = blockIdx.x / tnCount;
  const int tileM = tm << 7;
  const int tileN = tn << 7;

  const long long bOff = bStrideB ? (long long)(tileM >> 8) * bStrideB : 0;
  const u16* Bh_t = Bhg + bOff + (long long)tileN * K;

  f32x4 acc[4][4];
  #pragma unroll
  for (int i=0;i<4;i++)
    #pragma unroll
    for (int j=0;j<4;j++){
      acc[i][j][0]=0.f; acc[i][j][1]=0.f; acc[i][j][2]=0.f; acc[i][j][3]=0.f;
    }

  for (int kt = 0; kt < K; kt += 64){
    stage_tile<128,4>(Ag + (long long)tileM * K + kt, K, sA, lane, wave);
    stage_tile<128,4>(Bh_t + kt, K, sB, lane, wave);
    __syncthreads();
    #pragma unroll
    for (int kk=0;kk<2;kk++){
      bf16x8 a[4], b[4];
      #pragma unroll
      for (int i=0;i<4;i++){
        a[i] = ldfrag(sA, wm*64 + i*16, kk, lane);
        b[i] = ldfrag(sB, wn*64 + i*16, kk, lane);
      }
      #pragma unroll
      for (int mt=0;mt<4;mt++)
        #pragma unroll
        for (int nt=0;nt<4;nt++)
          acc[mt][nt] = __builtin_amdgcn_mfma_f32_16x16x32_bf16(a[mt], b[nt], acc[mt][nt], 0,0,0);
    }
    __syncthreads();
  }

  #pragma unroll
  for (int mt=0;mt<4;mt++)
    #pragma unroll
    for (int nt=0;nt<4;nt++){
      const int gr = tileM + wm*64 + mt*16 + ((lane >> 4) << 2);
      const int gc = tileN + wn*64 + nt*16 + (lane & 15);
      const float bb = bias ? bias[gc] : 0.f;
      f32x4 v = acc[mt][nt];
      if (WMODE == 0){
        float* o = (float*)Co + (long long)gr * N + gc;
        #pragma unroll
        for (int r=0;r<4;r++) o[(long long)r * N] = v[r] + bb;
      } else {
        u16* o = (u16*)Co + (long long)gr * N + gc;
        #pragma unroll
        for (int r=0;r<4;r++) o[(long long)r * N] = f2bf(v[r] + bb);
      }
    }
}

// ---------------------------------------------------------------------------
// K3: logits[b,n,:] = sum_m klT[n][m] * qT[b][:,m]  (split 3-pass), then
// row-softmax over qq (full 256 in-block), store attT[b][qq][n] bf16.
// Block = (b, ntile): 64 rows x 256 cols, K=256.
// ---------------------------------------------------------------------------
__global__ __launch_bounds__(256, 1)
void k_logits(const u16* __restrict__ qTh, const u16* __restrict__ qTl,
              const u16* __restrict__ klTh, const u16* __restrict__ klTl,
              u16* __restrict__ attT)
{
  __shared__ __align__(16) union U {
    struct S { u16 Ah[64*64]; u16 Al[64*64]; u16 Bh[256*64]; u16 Bl[256*64]; } s; // 80 KB
    float L[64*260];                                                              // 65 KB
  } u;
  __shared__ float rmax[64], rinv[64];

  const int tid  = threadIdx.x;
  const int lane = tid & 63;
  const int wave = tid >> 6;
  const int bidx  = blockIdx.x >> 2;
  const int ntile = blockIdx.x & 3;

  f32x4 acc[4][4];
  #pragma unroll
  for (int i=0;i<4;i++)
    #pragma unroll
    for (int j=0;j<4;j++){
      acc[i][j][0]=0.f; acc[i][j][1]=0.f; acc[i][j][2]=0.f; acc[i][j][3]=0.f;
    }

  for (int kt=0; kt<256; kt+=64){
    stage_tile<64,4> (klTh + (ntile << 6)*256 + kt, 256, u.s.Ah, lane, wave);
    stage_tile<64,4> (klTl + (ntile << 6)*256 + kt, 256, u.s.Al, lane, wave);
    stage_tile<256,4>(qTh + ((long long)bidx << 16) + kt, 256, u.s.Bh, lane, wave);
    stage_tile<256,4>(qTl + ((long long)bidx << 16) + kt, 256, u.s.Bl, lane, wave);
    __syncthreads();
    #pragma unroll
    for (int kk=0;kk<2;kk++){
      bf16x8 a[4], al[4], b[4], bl[4];
      #pragma unroll
      for (int i=0;i<4;i++){
        a[i]  = ldfrag(u.s.Ah, i*16, kk, lane);
        al[i] = ldfrag(u.s.Al, i*16, kk, lane);
        b[i]  = ldfrag(u.s.Bh, wave*64 + i*16, kk, lane);
        bl[i] = ldfrag(u.s.Bl, wave*64 + i*16, kk, lane);
      }
      #pragma unroll
      for (int mt=0;mt<4;mt++)
        #pragma unroll
        for (int nt=0;nt<4;nt++){
          acc[mt][nt] = __builtin_amdgcn_mfma_f32_16x16x32_bf16(a[mt],  b[nt],  acc[mt][nt], 0,0,0);
          acc[mt][nt] = __builtin_amdgcn_mfma_f32_16x16x32_bf16(al[mt], b[nt],  acc[mt][nt], 0,0,0);
          acc[mt][nt] = __builtin_amdgcn_mfma_f32_16x16x32_bf16(a[mt],  bl[nt], acc[mt][nt], 0,0,0);
        }
    }
    __syncthreads();
  }

  // dump logits (K_DIM=1 => scale 1) into L [64][260]
  #pragma unroll
  for (int mt=0;mt<4;mt++)
    #pragma unroll
    for (int nt=0;nt<4;nt++){
      const int r0 = mt*16 + ((lane >> 4) << 2);
      const int c  = wave*64 + nt*16 + (lane & 15);
      #pragma unroll
      for (int r=0;r<4;r++) u.L[(r0 + r)*260 + c] = acc[mt][nt][r];
    }
  __syncthreads();

  // row max & sum(exp): 4 threads per row
  {
    const int row = tid >> 2, sub = tid & 3;
    const float* Lr = &u.L[row*260 + sub*64];
    float mx = -3.4e38f;
    for (int i=0;i<64;i++) mx = fmaxf(mx, Lr[i]);
    mx = fmaxf(mx, __shfl_xor(mx, 1, 64));
    mx = fmaxf(mx, __shfl_xor(mx, 2, 64));
    float s = 0.f;
    for (int i=0;i<64;i++) s += __expf(Lr[i] - mx);
    s += __shfl_xor(s, 1, 64);
    s += __shfl_xor(s, 2, 64);
    if (sub == 0){ rmax[row] = mx; rinv[row] = 1.f / s; }
  }
  __syncthreads();

  // transposed store: thread qq writes attT[b][qq][ntile*64 .. +64)
  {
    const int qq = tid;
    u16* dst = attT + ((long long)bidx << 16) + qq*256 + (ntile << 6);
    #pragma unroll
    for (int n0=0;n0<64;n0+=8){
      bf16x8 pk;
      #pragma unroll
      for (int e=0;e<8;e++){
        int n = n0 + e;
        float v = __expf(u.L[n*260 + qq] - rmax[n]) * rinv[n];
        pk[e] = (short)f2bf(v);
      }
      *(bf16x8*)(dst + n0) = pk;
    }
  }
}

// split a fp32 array into bf16 hi/lo
__global__ void k_split(const float* __restrict__ w, u16* __restrict__ hi,
                        u16* __restrict__ lo, int n4){
  int i = blockIdx.x * blockDim.x + threadIdx.x;
  if (i >= n4) return;
  f32x4 v = ((const f32x4*)w)[i];
  u16x4 h, l;
  #pragma unroll
  for (int e=0;e<4;e++){
    u16 hh = f2bf(v[e]);
    h[e] = hh;
    l[e] = f2bf(v[e] - bf2f(hh));
  }
  ((u16x4*)hi)[i] = h;
  ((u16x4*)lo)[i] = l;
}

extern "C" void kernel_launch(void* const* d_in, const int* in_sizes, int n_in,
                              void* d_out, int out_size, void* d_ws, size_t ws_size,
                              hipStream_t stream){
  (void)in_sizes; (void)n_in; (void)out_size; (void)ws_size;
  const float* x  = (const float*)d_in[0];
  const float* Wq = (const float*)d_in[1];
  const float* bq = (const float*)d_in[2];
  const float* Wk = (const float*)d_in[3];
  const float* bk = (const float*)d_in[4];
  const float* Wv = (const float*)d_in[5];
  const float* bv = (const float*)d_in[6];
  const float* Wo = (const float*)d_in[7];
  const float* bo = (const float*)d_in[8];

  // scratch carved from d_out (dead before K5 rewrites it) + d_ws
  char* ob = (char*)d_out;
  u16* qTh  = (u16*)(ob);                          // 33.5 MB
  u16* qTl  = (u16*)(ob + (size_t)33554432);       // 33.5 MB
  u16* vh   = (u16*)(ob + (size_t)67108864);       // 33.5 MB
  u16* attT = (u16*)(ob + (size_t)100663296);      // 33.5 MB
  char* wb = (char*)d_ws;
  u16* omh  = (u16*)(wb);                          // 33.5 MB
  u16* Wqh  = (u16*)(wb + (size_t)33554432);
  u16* Wql  = Wqh + 262144;
  u16* Wvh  = Wql + 262144;
  u16* Wvl  = Wvh + 262144;
  u16* Woh  = Wvl + 262144;
  u16* Wol  = Woh + 262144;
  u16* klTh = Wol + 262144;                        // 128 KB
  u16* klTl = klTh + 65536;                        // total ws ~36.9 MB

  k_split<<<256, 256, 0, stream>>>(Wq, Wqh, Wql, 65536);
  k_split<<<256, 256, 0, stream>>>(Wv, Wvh, Wvl, 65536);
  k_split<<<256, 256, 0, stream>>>(Wo, Woh, Wol, 65536);

  // fused q(split)/v/klin: reads x once
  k_qvkl<<<512, 512, 0, stream>>>(x, Wqh, Wql, Wvh, Wk, bk, bq, bv,
                                  qTh, qTl, vh, klTh, klTl);
  // K3: logits + softmax -> attT
  k_logits<<<1024, 256, 0, stream>>>(qTh, qTl, klTh, klTl, attT);
  // K4: om = v @ att (B batched per b), N=256, K=256
  k_gemm<1><<<1024, 256, 0, stream>>>(vh, attT, 256, 256, 2, 65536, nullptr, omh);
  // K5: out = om @ Wo^T + bo (fp32 out), N=1024, K=256
  k_gemm<0><<<4096, 256, 0, stream>>>(omh, Woh, 1024, 256, 8, 0, bo, d_out);
}